// Round 9
// baseline (188.052 us; speedup 1.0000x reference)
//
#include <hip/hip_runtime.h>
#include <hip/hip_bf16.h>

typedef __attribute__((ext_vector_type(4))) float f32x4;
typedef __attribute__((ext_vector_type(8))) short bf16x8;

#define MFMA(a,b,c) __builtin_amdgcn_mfma_f32_16x16x32_bf16((a),(b),(c),0,0,0)

// Round-to-nearest split of fp32 into hi+lo bf16 (hi = RN(a), lo = RN(a - hi)).
__device__ inline void split_bf16(float a, unsigned short &h, unsigned short &l) {
    unsigned u = __float_as_uint(a);
    unsigned rh = (u + 0x7FFFu + ((u >> 16) & 1u)) & 0xFFFF0000u;
    float hf = __uint_as_float(rh);
    h = (unsigned short)(rh >> 16);
    float lf = a - hf;                      // exact (Sterbenz)
    unsigned u2 = __float_as_uint(lf);
    l = (unsigned short)((u2 + 0x7FFFu + ((u2 >> 16) & 1u)) >> 16);
}

__device__ inline unsigned short bf16_rn(float a) {
    unsigned u = __float_as_uint(a);
    return (unsigned short)((u + 0x7FFFu + ((u >> 16) & 1u)) >> 16);
}

__device__ inline float tanh_fast(float x) {
    float e = __expf(2.f * x);
    return 1.f - 2.f * __builtin_amdgcn_rcpf(e + 1.f);
}

__device__ inline bf16x8 ldb(const unsigned short* p) { return *(const bf16x8*)p; }
// 16B load safe at 4B alignment (memcpy lets the backend pick legal width)
__device__ inline f32x4 ld4u(const float* p) { f32x4 v; __builtin_memcpy(&v, p, 16); return v; }

// ---------------- merged prep: W_eff fold (hi/lo) + layer packs (bf16) ------
// Pack layout (bf16): [ktile][otile][lane][8], lane = (o&15) + 16*((k>>3)&3), j = k&7
__global__ void prep_all(const float* __restrict__ mix_a,
                         const float* __restrict__ w1, const float* __restrict__ w2,
                         const float* __restrict__ w3, const float* __restrict__ wf,
                         unsigned short* __restrict__ wph, unsigned short* __restrict__ wpl,
                         unsigned short* __restrict__ wlh, unsigned short* __restrict__ wfh) {
    int idx = blockIdx.x * 256 + threadIdx.x;
    if (idx < 128 * 384) {
        int o = idx / 384;
        int k = idx - o * 384;
        float acc = 0.f;
        if (k < 363) {
            int c = k / 121, rem = k - c * 121;
            int y = rem / 11, x = rem - y * 11;
            const float* ma = mix_a + (size_t)o * 1215 + c * 81;
            auto add = [&](int f, int i, int j, float coef) {
                int n = y - i, m = x - j;
                if (n >= 0 && n < 9 && m >= 0 && m < 9)
                    acc += ma[f * 243 + n * 9 + m] * coef;
            };
            add(0, 1, 1, 1.f);
            add(1, 0, 1, -5.f);  add(1, 2, 1, 5.f);
            add(2, 1, 0, -5.f);  add(2, 1, 2, 5.f);
            add(3, 0, 1, 100.f); add(3, 1, 1, -200.f); add(3, 2, 1, 100.f);
            add(4, 1, 0, 100.f); add(4, 1, 1, -200.f); add(4, 1, 2, 100.f);
        }
        unsigned short h, l; split_bf16(acc, h, l);
        int kt = k >> 5, ot = o >> 4;
        int lane = (o & 15) + 16 * ((k >> 3) & 3);
        int pidx = ((kt * 8 + ot) * 64 + lane) * 8 + (k & 7);
        wph[pidx] = h; wpl[pidx] = l;
        return;
    }
    idx -= 128 * 384;
    if (idx < 3 * 16384) {
        int layer = idx >> 14; int rem = idx & 16383;
        int o = rem >> 7, k = rem & 127;
        const float* w = (layer == 0) ? w1 : ((layer == 1) ? w2 : w3);
        float v = w[o * 128 + k];
        int kt = k >> 5, ot = o >> 4;
        int lane = (o & 15) + 16 * ((k >> 3) & 3);
        int pidx = layer * 16384 + ((kt * 8 + ot) * 64 + lane) * 8 + (k & 7);
        wlh[pidx] = bf16_rn(v);
    } else if (idx < 3 * 16384 + 2048) {
        int rem = idx - 3 * 16384;
        int o = rem >> 7, k = rem & 127;
        float v = (o < 5) ? wf[o * 128 + k] : 0.f;
        int kt = k >> 5;
        int lane = (o & 15) + 16 * ((k >> 3) & 3);
        int pidx = (kt * 64 + lane) * 8 + (k & 7);
        wfh[pidx] = bf16_rn(v);
    }
}

// ---- fused main: 2 M-tiles/wave (32 samples), dbuf LDS B, 1 barrier/step ---
// Unified slice pipeline u=0..24: u<12 stage-1 (H+L), 12..23 layers (H), 24 wf.
// Step u: ds_write slice u+1 (from pre regs) -> buf[(u+1)&1]; load slice u+2;
//         compute on buf[u&1]; barrier.
__global__ __launch_bounds__(256, 2)
void fused_main(const float* __restrict__ data,
                const float* __restrict__ mix_b,
                const float* __restrict__ b1v,
                const float* __restrict__ b2v,
                const float* __restrict__ b3v,
                const float* __restrict__ bfv,
                const unsigned short* __restrict__ wp1h,
                const unsigned short* __restrict__ wp1l,
                const unsigned short* __restrict__ wlh,
                const unsigned short* __restrict__ wfh,
                float* __restrict__ out, int Btot) {
    __shared__ __align__(16) unsigned short BstH[2][4096];     // 16 KB (dbuf hi)
    __shared__ __align__(16) unsigned short BstL[2][4096];     // 16 KB (dbuf lo)
    __shared__ __align__(16) unsigned short XsH[4][2][16][136];// 34,816 B

    const int t    = threadIdx.x;
    const int wave = t >> 6;
    const int lane = t & 63;
    const int col  = lane & 15;
    const int kg   = lane >> 4;
    const int s0   = blockIdx.x * 128 + wave * 32;

    int r0 = s0 + col, r1 = s0 + 16 + col;
    if (r0 >= Btot) r0 = Btot - 1;        // clamp loads; stores masked below
    if (r1 >= Btot) r1 = Btot - 1;
    const float* arow0 = data + (size_t)r0 * 363;
    const float* arow1 = data + (size_t)r1 * 363;

    // ---- prologue: slice 0 -> buf0, slice 1 -> pre regs ----
    bf16x8 pH0 = ldb(wp1h + t * 8), pH1 = ldb(wp1h + 2048 + t * 8);
    bf16x8 pL0 = ldb(wp1l + t * 8), pL1 = ldb(wp1l + 2048 + t * 8);

    f32x4 acc[2][8];
    #pragma unroll
    for (int ot = 0; ot < 8; ++ot) {
        float b = mix_b[col + 16 * ot];
        acc[0][ot] = (f32x4){b, b, b, b};
        acc[1][ot] = (f32x4){b, b, b, b};
    }
    f32x4 a4[2][2][2];                    // [pp][tile][half]
    a4[0][0][0] = ld4u(arow0 + kg * 8);  a4[0][0][1] = ld4u(arow0 + kg * 8 + 4);
    a4[0][1][0] = ld4u(arow1 + kg * 8);  a4[0][1][1] = ld4u(arow1 + kg * 8 + 4);

    *(bf16x8*)&BstH[0][t * 8] = pH0;  *(bf16x8*)&BstH[0][2048 + t * 8] = pH1;
    *(bf16x8*)&BstL[0][t * 8] = pL0;  *(bf16x8*)&BstL[0][2048 + t * 8] = pL1;
    pH0 = ldb(wp1h + 4096 + t * 8); pH1 = ldb(wp1h + 4096 + 2048 + t * 8);
    pL0 = ldb(wp1l + 4096 + t * 8); pL1 = ldb(wp1l + 4096 + 2048 + t * 8);
    __syncthreads();

    // ---- stage 1: steps u = 0..11 (K chunks of 32) ----
    #pragma unroll
    for (int u = 0; u < 12; ++u) {
        const int cur = u & 1;
        // write slice u+1 (loaded last step) into the other buffer
        *(bf16x8*)&BstH[cur ^ 1][t * 8] = pH0;
        *(bf16x8*)&BstH[cur ^ 1][2048 + t * 8] = pH1;
        if (u < 11) {
            *(bf16x8*)&BstL[cur ^ 1][t * 8] = pL0;
            *(bf16x8*)&BstL[cur ^ 1][2048 + t * 8] = pL1;
        }
        // issue loads for slice u+2
        if (u < 10) {
            const unsigned short* nh = wp1h + (size_t)(u + 2) * 4096;
            const unsigned short* nl = wp1l + (size_t)(u + 2) * 4096;
            pH0 = ldb(nh + t * 8); pH1 = ldb(nh + 2048 + t * 8);
            pL0 = ldb(nl + t * 8); pL1 = ldb(nl + 2048 + t * 8);
        } else {                          // slices 12,13 = layer slices 0,1 (hi only)
            const unsigned short* nh = wlh + (size_t)(u - 10) * 4096;
            pH0 = ldb(nh + t * 8); pH1 = ldb(nh + 2048 + t * 8);
        }
        // A prefetch for step u+1
        if (u < 10) {
            const int kb = (u + 1) * 32 + kg * 8;     // max 351, in-bounds
            a4[cur ^ 1][0][0] = ld4u(arow0 + kb); a4[cur ^ 1][0][1] = ld4u(arow0 + kb + 4);
            a4[cur ^ 1][1][0] = ld4u(arow1 + kb); a4[cur ^ 1][1][1] = ld4u(arow1 + kb + 4);
        } else if (u == 10) {             // chunk 11: masked tail (k >= 363 -> 0)
            #pragma unroll
            for (int i = 0; i < 2; ++i)
                #pragma unroll
                for (int j = 0; j < 4; ++j) {
                    int k = 352 + kg * 8 + i * 4 + j;
                    bool ok = (k < 363);
                    a4[cur ^ 1][0][i][j] = ok ? arow0[k] : 0.f;
                    a4[cur ^ 1][1][i][j] = ok ? arow1[k] : 0.f;
                }
        }
        // split current A chunk (both tiles) into hi/lo fragments
        bf16x8 ah0, al0, ah1, al1;
        #pragma unroll
        for (int i = 0; i < 2; ++i)
            #pragma unroll
            for (int j = 0; j < 4; ++j) {
                unsigned short hh, ll;
                split_bf16(a4[cur][0][i][j], hh, ll);
                ah0[i * 4 + j] = (short)hh; al0[i * 4 + j] = (short)ll;
                split_bf16(a4[cur][1][i][j], hh, ll);
                ah1[i * 4 + j] = (short)hh; al1[i * 4 + j] = (short)ll;
            }
        // 16 LDS fragment reads feed 48 MFMA (bh reused 4x, bl 2x)
        #pragma unroll
        for (int ot = 0; ot < 8; ++ot) {
            bf16x8 bh = *(const bf16x8*)&BstH[cur][(ot * 64 + lane) * 8];
            acc[0][ot] = MFMA(ah0, bh, acc[0][ot]);
            acc[1][ot] = MFMA(ah1, bh, acc[1][ot]);
            acc[0][ot] = MFMA(al0, bh, acc[0][ot]);
            acc[1][ot] = MFMA(al1, bh, acc[1][ot]);
        }
        #pragma unroll
        for (int ot = 0; ot < 8; ++ot) {
            bf16x8 bl = *(const bf16x8*)&BstL[cur][(ot * 64 + lane) * 8];
            acc[0][ot] = MFMA(ah0, bl, acc[0][ot]);
            acc[1][ot] = MFMA(ah1, bl, acc[1][ot]);
        }
        __syncthreads();
    }

    // mixed -> tanh -> Xs (both tiles; bf16 is exact for saturated values)
    #pragma unroll
    for (int tt = 0; tt < 2; ++tt)
        #pragma unroll
        for (int ot = 0; ot < 8; ++ot)
            #pragma unroll
            for (int j = 0; j < 4; ++j)
                XsH[wave][tt][kg * 4 + j][col + 16 * ot] = bf16_rn(tanh_fast(acc[tt][ot][j]));
    asm volatile("s_waitcnt lgkmcnt(0)" ::: "memory");   // in-wave X visibility

    // ---- 3 hidden layers: pipeline steps u = 12..23 ----
    const float* biases[3] = {b1v, b2v, b3v};
    #pragma unroll
    for (int layer = 0; layer < 3; ++layer) {
        const float* bb = biases[layer];
        f32x4 nacc[2][8];
        #pragma unroll
        for (int ot = 0; ot < 8; ++ot) {
            float b = bb[col + 16 * ot];
            nacc[0][ot] = (f32x4){b, b, b, b};
            nacc[1][ot] = (f32x4){b, b, b, b};
        }
        #pragma unroll
        for (int kt = 0; kt < 4; ++kt) {
            const int u = 12 + layer * 4 + kt;
            const int cur = u & 1;
            // write slice u+1
            *(bf16x8*)&BstH[cur ^ 1][t * 8] = pH0;
            if (u < 23) *(bf16x8*)&BstH[cur ^ 1][2048 + t * 8] = pH1;
            // load slice u+2
            if (u < 22) {
                const unsigned short* nh = wlh + (size_t)(u - 10) * 4096;
                pH0 = ldb(nh + t * 8); pH1 = ldb(nh + 2048 + t * 8);
            } else if (u == 22) {
                pH0 = ldb(wfh + t * 8);          // wf slice: 2048 ushorts only
            }
            bf16x8 xh0 = *(const bf16x8*)&XsH[wave][0][col][kt * 32 + kg * 8];
            bf16x8 xh1 = *(const bf16x8*)&XsH[wave][1][col][kt * 32 + kg * 8];
            #pragma unroll
            for (int ot = 0; ot < 8; ++ot) {
                bf16x8 bh = *(const bf16x8*)&BstH[cur][(ot * 64 + lane) * 8];
                nacc[0][ot] = MFMA(xh0, bh, nacc[0][ot]);
                nacc[1][ot] = MFMA(xh1, bh, nacc[1][ot]);
            }
            __syncthreads();
        }
        asm volatile("s_waitcnt lgkmcnt(0)" ::: "memory");   // X reads done
        #pragma unroll
        for (int tt = 0; tt < 2; ++tt)
            #pragma unroll
            for (int ot = 0; ot < 8; ++ot)
                #pragma unroll
                for (int j = 0; j < 4; ++j)
                    XsH[wave][tt][kg * 4 + j][col + 16 * ot] = bf16_rn(tanh_fast(nacc[tt][ot][j]));
        asm volatile("s_waitcnt lgkmcnt(0)" ::: "memory");   // X writes visible
    }

    // ---- final layer 128 -> 5 (N padded to 16); slice 24 is in buf[0] ----
    float fb = (col < 5) ? bfv[col] : 0.f;
    f32x4 facc[2];
    facc[0] = (f32x4){fb, fb, fb, fb};
    facc[1] = (f32x4){fb, fb, fb, fb};
    #pragma unroll
    for (int kt = 0; kt < 4; ++kt) {
        bf16x8 fh = *(const bf16x8*)&BstH[0][(kt * 64 + lane) * 8];
        bf16x8 xh0 = *(const bf16x8*)&XsH[wave][0][col][kt * 32 + kg * 8];
        bf16x8 xh1 = *(const bf16x8*)&XsH[wave][1][col][kt * 32 + kg * 8];
        facc[0] = MFMA(xh0, fh, facc[0]);
        facc[1] = MFMA(xh1, fh, facc[1]);
    }
    if (col < 5) {
        #pragma unroll
        for (int tt = 0; tt < 2; ++tt)
            #pragma unroll
            for (int j = 0; j < 4; ++j) {
                int s = s0 + 16 * tt + kg * 4 + j;
                if (s < Btot) out[(size_t)s * 5 + col] = facc[tt][j];
            }
    }
}

extern "C" void kernel_launch(void* const* d_in, const int* in_sizes, int n_in,
                              void* d_out, int out_size, void* d_ws, size_t ws_size,
                              hipStream_t stream) {
    const float* data  = (const float*)d_in[0];
    const float* mix_a = (const float*)d_in[1];
    const float* mix_b = (const float*)d_in[2];
    const float* w1    = (const float*)d_in[3];
    const float* b1    = (const float*)d_in[4];
    const float* w2    = (const float*)d_in[5];
    const float* b2    = (const float*)d_in[6];
    const float* w3    = (const float*)d_in[7];
    const float* b3    = (const float*)d_in[8];
    const float* wf    = (const float*)d_in[9];
    const float* bf    = (const float*)d_in[10];
    float* out = (float*)d_out;
    int Btot = in_sizes[0] / 363;

    if (ws_size < 299008) return;   // wp1h+wp1l+wlh+wfh = 149,504 ushorts
    unsigned short* wp1h = (unsigned short*)d_ws;      // 49152 ushorts
    unsigned short* wp1l = wp1h + 49152;               // 49152
    unsigned short* wlh  = wp1l + 49152;               // 3*16384
    unsigned short* wfh  = wlh + 49152;                // 2048

    prep_all<<<392, 256, 0, stream>>>(mix_a, w1, w2, w3, wf,
                                      wp1h, wp1l, wlh, wfh);
    int blocks = (Btot + 127) / 128;
    fused_main<<<blocks, 256, 0, stream>>>(data, mix_b, b1, b2, b3, bf,
                                           wp1h, wp1l, wlh, wfh, out, Btot);
}